// Round 5
// baseline (464.098 us; speedup 1.0000x reference)
//
#include <hip/hip_runtime.h>
#include <hip/hip_bf16.h>
#include <stdint.h>

typedef __bf16 bf16_t;
typedef __bf16 bf16x4 __attribute__((ext_vector_type(4)));
typedef __bf16 bf16x8 __attribute__((ext_vector_type(8)));
typedef float f32x4 __attribute__((ext_vector_type(4)));
typedef float f32x16 __attribute__((ext_vector_type(16)));

static_assert(sizeof(bf16x8) == 16, "bf16x8 must be 16B");

#define MFMA_BF16(a, b, c) __builtin_amdgcn_mfma_f32_16x16x32_bf16((a), (b), (c), 0, 0, 0)
// 32x32x16 bf16 MFMA. Layout (CDNA4 family):
//   A[row=lane&31][k=(lane>>5)*8+i]  B[k=(lane>>5)*8+i][col=lane&31]
//   C/D: col=lane&31, row=(reg&3)+8*(reg>>2)+4*(lane>>5)   [guide-verified m74/m101]
#define MFMA32(a, b, c) __builtin_amdgcn_mfma_f32_32x32x16_bf16((a), (b), (c), 0, 0, 0)

typedef const __attribute__((address_space(1))) void* gas_ptr;
typedef __attribute__((address_space(3))) void* las_ptr;

__device__ __forceinline__ void gload_lds16(const void* g, void* l) {
  __builtin_amdgcn_global_load_lds((gas_ptr)g, (las_ptr)l, 16, 0, 0);
}

// compile-time memory-op ordering fence (pins global_load issue order)
#define ORDER_FENCE() asm volatile("" ::: "memory")

#define NEG_BIG (-1.0e30f)

// ---------------------------------------------------------------------------
// fp32 -> bf16 convert, all three inputs in one launch.
// ---------------------------------------------------------------------------
__global__ __launch_bounds__(256) void cvt3_kernel(
    const float* __restrict__ x, const float* __restrict__ wq,
    const float* __restrict__ wp, bf16_t* __restrict__ xb,
    bf16_t* __restrict__ wqb, bf16_t* __restrict__ wpb) {
  const int i = (blockIdx.x * 256 + threadIdx.x) * 4;
  const float* src;
  bf16_t* dst;
  int off;
  if (i < 8388608) {
    src = x; dst = xb; off = 0;
  } else if (i < 9175040) {
    src = wq; dst = wqb; off = 8388608;
  } else {
    src = wp; dst = wpb; off = 9175040;
  }
  const f32x4 v = *(const f32x4*)(src + (i - off));
  bf16x4 o;
  o[0] = (bf16_t)v[0];
  o[1] = (bf16_t)v[1];
  o[2] = (bf16_t)v[2];
  o[3] = (bf16_t)v[3];
  *(bf16x4*)(dst + (i - off)) = o;
}

// ---------------------------------------------------------------------------
// GEMM (m97 structure): D[m][n] = sum_k A[m][k] * Bw[n][k]   (unchanged)
// ---------------------------------------------------------------------------
template <int MODE>
__global__ __launch_bounds__(256, 2) void gemm_bt_kernel(
    const bf16_t* __restrict__ A, const bf16_t* __restrict__ Bw,
    bf16_t* __restrict__ o_q, bf16_t* __restrict__ o_k, bf16_t* __restrict__ o_vT,
    float* __restrict__ o_f) {
  constexpr int K = 512;
  __shared__ bf16_t As[128 * 32];
  __shared__ bf16_t Bs[128 * 32];

  const int tid = threadIdx.x;
  const int lane = tid & 63;
  const int wid = tid >> 6;
  const int quad = lane >> 4;
  const int l15 = lane & 15;
  const int wm = wid >> 1;
  const int wn = wid & 1;

  const int mt = blockIdx.x & 127;
  const int nt = blockIdx.x >> 7;
  const int row0 = mt * 128;
  const int col0 = nt * 128;

  f32x4 acc[4][4] = {};

  for (int kt = 0; kt < K; kt += 32) {
    __syncthreads();
#pragma unroll
    for (int rnd = 0; rnd < 2; rnd++) {
      const int e = (rnd * 256 + tid) * 8;
      const int r = e >> 5;
      const int c = e & 31;
      gload_lds16(A + (size_t)(row0 + r) * K + kt + c, As + e);
      gload_lds16(Bw + (size_t)(col0 + r) * K + kt + c, Bs + e);
    }
    __syncthreads();

    bf16x8 af[4], bfr[4];
#pragma unroll
    for (int i = 0; i < 4; i++)
      af[i] = *(const bf16x8*)(As + (wm * 64 + i * 16 + l15) * 32 + quad * 8);
#pragma unroll
    for (int i = 0; i < 4; i++)
      bfr[i] = *(const bf16x8*)(Bs + (wn * 64 + i * 16 + l15) * 32 + quad * 8);
#pragma unroll
    for (int mi = 0; mi < 4; mi++)
#pragma unroll
      for (int ni = 0; ni < 4; ni++)
        acc[mi][ni] = MFMA_BF16(af[mi], bfr[ni], acc[mi][ni]);
  }

#pragma unroll
  for (int mi = 0; mi < 4; mi++) {
    const int row = row0 + wm * 64 + mi * 16 + quad * 4;
#pragma unroll
    for (int ni = 0; ni < 4; ni++) {
      const int col = col0 + wn * 64 + ni * 16 + l15;
#pragma unroll
      for (int r = 0; r < 4; r++) {
        const int rr = row + r;
        if constexpr (MODE == 0) {
          const bf16_t bv = (bf16_t)acc[mi][ni][r];
          if (col < 512) {
            o_q[(size_t)rr * 512 + col] = bv;
          } else if (col < 1024) {
            o_k[(size_t)rr * 512 + (col - 512)] = bv;
          } else {
            const int bb = rr >> 12;
            const int t = rr & 4095;
            o_vT[((size_t)bb * 512 + (col - 1024)) * 4096 + t] = bv;
          }
        } else {
          o_f[(size_t)rr * 512 + col] = acc[mi][ni][r];
        }
      }
    }
  }
}

// ---------------------------------------------------------------------------
// Split-KV flash attention stage 1 — 32x32x16 MFMA, counted-vmcnt pipeline.
// Block (b, s, c): 64 q-rows, 512-kv chunk, full 512-d output. Grid = 1152.
// Waves: wid = wq + 2*wk;  wq = q-half (32 q), wk = kv-half (phase1) = d-half
// (phase3).
//  Slices (all 32 KB, 8 gload_lds16/thread, dense conflict-free layouts via
//  source-permuted staging, rule #21):
//   u<16:   K-slice  [16 mg][2 kk2][2 h][32 l31] chunks of K[mg*32+l31][d8]
//   u>=16:  V-slice  [16 dg][2 c2][2 h][32 l31] chunks of V^T rows (32-kv chunk)
//  Phase 1: S^T tile = MFMA32(A=K, B=Q): per slice 16 A-reads (each a dense
//   1024-B wave read) for 16 MFMAs; Q B-frags rotate from global, loaded
//   1-ahead BEFORE the stage so vmcnt(8) stays exact.
//  Phase 2: per-lane softmax (lane = one q-row), 1 shfl + cross-wk LDS
//   exchange (raw lgkm barriers only — V prefetches stay in flight).
//  Phase 3: O tile = MFMA32(A=P from 4-KB dbuf P_lds, B=V). P chunk c+1 is
//   ds-written by its owner wave during iter c. 18 dense reads / 16 MFMAs.
//  Epilogue: partO stored as dense 512-B-per-instruction runs:
//   flat = bid*32768 + (dh*2+wq)*8192 + dt*1024 + rr*256 + h*128 + l31*4 + j
//   with q = wq*32+8rr+4h+j, d = dh*256+dt*32+l31.  No RMW.
// ---------------------------------------------------------------------------
__global__ __launch_bounds__(256, 2) void attn_part_kernel(
    const bf16_t* __restrict__ q, const bf16_t* __restrict__ k,
    const bf16_t* __restrict__ vT, bf16_t* __restrict__ partO,
    float2* __restrict__ stats) {
  __shared__ bf16_t SB[2][16384];  // 2 x 32 KB slice double buffer
  __shared__ bf16_t PL[2][2048];   // 2 x 4 KB P-chunk double buffer
  __shared__ float SMX[2][2][32];  // [wq][wk][l31] max exchange
  __shared__ float SLR[2][2][32];  // [wq][wk][l31] sum exchange

  const int tid = threadIdx.x;
  const int lane = tid & 63;
  const int wid = tid >> 6;
  const int h = lane >> 5;
  const int l31 = lane & 31;
  const int wq = wid & 1;
  const int wk = wid >> 1;

  const int bid = blockIdx.x;
  const int b = bid & 3;
  const int w = bid >> 2;  // 0..287
  int g = 0;
  while (w >= 4 * (g + 1) * (g + 2)) g++;
  const int rem = w - 4 * g * (g + 1);
  const int i = rem / (g + 1);
  const int c = rem - i * (g + 1);
  const int s = 8 * g + i;

  const int kv0 = c * 512;
  const int qmaxw = s * 64 + wq * 32 + 31;                 // wave's max q-row
  const int mtmax = min(7, (qmaxw - kv0 - wk * 256) >> 5); // live 32-kv tiles (may be <0)
  const int NC = min(16, ((s * 64 + 63 - kv0) >> 5) + 1);  // live 32-kv chunks, >=2, even

  const float scale = 0.044194173824159216f;  // 1/sqrt(512)
  const bf16_t* kbase = k + ((size_t)b * 4096 + kv0) * 512;
  const bf16_t* vbase = vT + ((size_t)b * 512) * 4096 + kv0;
  const bf16_t* qp =
      q + ((size_t)(b * 4096 + s * 64 + wq * 32 + l31)) * 512 + h * 8;

  // K-slice kt: chunk ch=(mg,kk2,hk,l31) <- K[kv0+mg*32+l31][kt*32+kk2*16+hk*8]
  auto stageK = [&](int kt, int buf) {
#pragma unroll
    for (int rnd = 0; rnd < 8; rnd++) {
      const int ch = rnd * 256 + tid;
      const int mg = ch >> 7, kk2 = (ch >> 6) & 1, hk = (ch >> 5) & 1, l = ch & 31;
      gload_lds16(kbase + (size_t)(mg * 32 + l) * 512 + kt * 32 + kk2 * 16 + hk * 8,
                  &SB[buf][ch * 8]);
    }
  };
  // V-slice chunk cc: ch=(dg,c2,hv,l31) <- vT[b*512+dg*32+l31][kv0+cc*32+c2*16+hv*8]
  auto stageV = [&](int cc, int buf) {
#pragma unroll
    for (int rnd = 0; rnd < 8; rnd++) {
      const int ch = rnd * 256 + tid;
      const int dg = ch >> 7, c2 = (ch >> 6) & 1, hv = (ch >> 5) & 1, l = ch & 31;
      gload_lds16(vbase + (size_t)(dg * 32 + l) * 4096 + cc * 32 + c2 * 16 + hv * 8,
                  &SB[buf][ch * 8]);
    }
  };

  // ---- prologue: Q(0) first, then slices 0,1 (order pinned) --------------
  bf16x8 qbuf[2][2];
  qbuf[0][0] = *(const bf16x8*)(qp + 0);
  qbuf[0][1] = *(const bf16x8*)(qp + 16);
  ORDER_FENCE();
  stageK(0, 0);
  ORDER_FENCE();
  stageK(1, 1);
  ORDER_FENCE();

  // ---- Phase 1: S^T accumulate (8 x 32x32 tiles per wave) ----------------
  f32x16 Sacc[8] = {};

  int cur = 0;
#pragma unroll
  for (int kt = 0; kt < 16; kt++) {
    asm volatile("s_waitcnt vmcnt(8)" ::: "memory");
    __builtin_amdgcn_sched_barrier(0);
    __builtin_amdgcn_s_barrier();
    const bf16_t* sb = &SB[cur][0];
    __builtin_amdgcn_s_setprio(1);
#pragma unroll
    for (int kk2 = 0; kk2 < 2; kk2++) {
#pragma unroll
      for (int mt = 0; mt < 8; mt++) {
        if (mt <= mtmax) {  // wave-uniform
          const bf16x8 kf = *(const bf16x8*)(
              sb + (wk * 8 + mt) * 1024 + kk2 * 512 + h * 256 + l31 * 8);
          Sacc[mt] = MFMA32(kf, qbuf[kt & 1][kk2], Sacc[mt]);
        }
      }
    }
    __builtin_amdgcn_s_setprio(0);
    asm volatile("s_waitcnt lgkmcnt(0)" ::: "memory");
    __builtin_amdgcn_sched_barrier(0);
    __builtin_amdgcn_s_barrier();
    if (kt < 15) {
      qbuf[(kt + 1) & 1][0] = *(const bf16x8*)(qp + (kt + 1) * 32);
      qbuf[(kt + 1) & 1][1] = *(const bf16x8*)(qp + (kt + 1) * 32 + 16);
      ORDER_FENCE();  // Q-loads issue BEFORE the stage -> vmcnt(8) exact
    }
    if (kt < 14)
      stageK(kt + 2, cur);
    else
      stageV(kt - 14, cur);  // V chunks 0,1 (NC >= 2 always)
    cur ^= 1;
  }

  // ---- Phase 2: softmax (lane = one q-row; raw barriers only) ------------
  const int qr = s * 64 + wq * 32 + l31;
  float mx = NEG_BIG;
#pragma unroll
  for (int mt = 0; mt < 8; mt++) {
    if (mt <= mtmax) {
#pragma unroll
      for (int rr = 0; rr < 4; rr++)
#pragma unroll
        for (int j = 0; j < 4; j++) {
          const int kvg = kv0 + wk * 256 + mt * 32 + 8 * rr + 4 * h + j;
          if (kvg <= qr) mx = fmaxf(mx, Sacc[mt][rr * 4 + j]);
        }
    }
  }
  mx = fmaxf(mx, __shfl_xor(mx, 32));
  if (lane < 32) SMX[wq][wk][l31] = mx;
  asm volatile("s_waitcnt lgkmcnt(0)" ::: "memory");
  __builtin_amdgcn_sched_barrier(0);
  __builtin_amdgcn_s_barrier();
  const float M = fmaxf(SMX[wq][0][l31], SMX[wq][1][l31]);

  float lrow = 0.0f;
  bf16x4 pb[8][4] = {};
#pragma unroll
  for (int mt = 0; mt < 8; mt++) {
    if (mt <= mtmax) {
#pragma unroll
      for (int rr = 0; rr < 4; rr++) {
        bf16x4 pv = {};
#pragma unroll
        for (int j = 0; j < 4; j++) {
          const int kvg = kv0 + wk * 256 + mt * 32 + 8 * rr + 4 * h + j;
          float p = 0.0f;
          if (kvg <= qr) p = __expf((Sacc[mt][rr * 4 + j] - M) * scale);
          pv[j] = (bf16_t)p;
          lrow += p;
        }
        pb[mt][rr] = pv;
      }
    }
  }
  lrow += __shfl_xor(lrow, 32);
  if (lane < 32) SLR[wq][wk][l31] = lrow;
  asm volatile("s_waitcnt lgkmcnt(0)" ::: "memory");
  __builtin_amdgcn_sched_barrier(0);
  __builtin_amdgcn_s_barrier();
  const float L = SLR[wq][0][l31] + SLR[wq][1][l31];
  if (wk == 0 && lane < 32)
    stats[((size_t)w * 4 + b) * 64 + wq * 32 + l31] = make_float2(M * scale, L);

  // write P chunk into PL[buf]: [wq][c2=rr>>1][hs=rr&1][l31] + byte 8h
  auto pwrite = [&](int mt, int buf) {
#pragma unroll
    for (int rr = 0; rr < 4; rr++) {
      *(bf16x4*)((char*)&PL[buf][0] + wq * 2048 + (rr >> 1) * 1024 +
                 (rr & 1) * 512 + l31 * 16 + 8 * h) = pb[mt][rr];
    }
  };
  if (wk == 0) pwrite(0, 0);  // chunk 0 (owner wk=0, both wq waves)
  asm volatile("s_waitcnt lgkmcnt(0)" ::: "memory");
  __builtin_amdgcn_sched_barrier(0);
  __builtin_amdgcn_s_barrier();

  // ---- Phase 3: O = P.V ; wave (wq, dh=wk), 8 d-tiles of 32 --------------
  const int dh = wk;
  f32x16 Oacc[8] = {};
#pragma unroll
  for (int cc = 0; cc < 16; cc++) {
    if (cc < NC) {  // block-uniform
      if (cc == NC - 1)
        asm volatile("s_waitcnt vmcnt(0)" ::: "memory");
      else
        asm volatile("s_waitcnt vmcnt(8)" ::: "memory");
      __builtin_amdgcn_sched_barrier(0);
      __builtin_amdgcn_s_barrier();
      const bf16_t* sb = &SB[cur][0];
      __builtin_amdgcn_s_setprio(1);
#pragma unroll
      for (int c2 = 0; c2 < 2; c2++) {
        const bf16x8 pA = *(const bf16x8*)(
            (const char*)&PL[cc & 1][0] + wq * 2048 + c2 * 1024 + h * 512 + l31 * 16);
#pragma unroll
        for (int dt = 0; dt < 8; dt++) {
          const bf16x8 vB = *(const bf16x8*)(
              sb + (dh * 8 + dt) * 1024 + c2 * 512 + h * 256 + l31 * 8);
          Oacc[dt] = MFMA32(pA, vB, Oacc[dt]);
        }
      }
      __builtin_amdgcn_s_setprio(0);
      if (cc + 1 < NC && wk == ((cc + 1) >> 3)) pwrite((cc + 1) & 7, (cc + 1) & 1);
      asm volatile("s_waitcnt lgkmcnt(0)" ::: "memory");
      __builtin_amdgcn_sched_barrier(0);
      __builtin_amdgcn_s_barrier();
      if (cc + 2 < NC) stageV(cc + 2, cur);
      cur ^= 1;
    }
  }

  // ---- epilogue: dense native-layout partO stores (512 B per instr) ------
  bf16_t* pbase = partO + (size_t)bid * 32768 + (size_t)(dh * 2 + wq) * 8192;
#pragma unroll
  for (int dt = 0; dt < 8; dt++) {
#pragma unroll
    for (int rr = 0; rr < 4; rr++) {
      bf16x4 ov;
#pragma unroll
      for (int j = 0; j < 4; j++) ov[j] = (bf16_t)Oacc[dt][rr * 4 + j];
      *(bf16x4*)(pbase + dt * 1024 + rr * 256 + h * 128 + l31 * 4) = ov;
    }
  }
}

// ---------------------------------------------------------------------------
// Stage 2: combine chunk partials per (b, s). Reads the native fragment
// layout coalesced (8-B per thread, dense per wave), weights+normalizes in
// registers, transposes through a 64-KB XOR-swizzled LDS bounce, writes
// coalesced bf16x8 rows.
// ---------------------------------------------------------------------------
__global__ __launch_bounds__(256) void attn_combine_kernel(
    const bf16_t* __restrict__ partO, const float2* __restrict__ stats,
    bf16_t* __restrict__ o) {
  const int b = blockIdx.x & 3;
  const int s = blockIdx.x >> 2;
  const int g = s >> 3;
  const int nc = g + 1;
  const int w0 = 4 * g * (g + 1) + (s & 7) * (g + 1);

  __shared__ float wgt[8][64];
  __shared__ float linv[64];
  __shared__ bf16_t TB[64 * 512];  // 64 KB transpose bounce

  const int tid = threadIdx.x;
  if (tid < 64) {
    float mc[8], lc[8];
    float M = NEG_BIG;
    for (int cc = 0; cc < nc; cc++) {
      const float2 ml = stats[((size_t)(w0 + cc) * 4 + b) * 64 + tid];
      mc[cc] = ml.x;
      lc[cc] = ml.y;
      M = fmaxf(M, ml.x);
    }
    float L = 0.0f;
    for (int cc = 0; cc < nc; cc++) {
      const float wv = __expf(mc[cc] - M);
      wgt[cc][tid] = wv;
      L += wv * lc[cc];
    }
    linv[tid] = (L > 0.0f) ? 1.0f / L : 0.0f;
  }
  __syncthreads();

  // thread = (rr, hh, l31); seg = (dh, wq, dt). q-quad = wq*32+8rr+4hh+j,
  // d = dh*256+dt*32+l31. flat element = bid*32768 + (seg*256 + tid)*4 + j.
  const int rr = tid >> 6;
  const int hh = (tid >> 5) & 1;
  const int l31 = tid & 31;

  for (int seg = 0; seg < 32; seg++) {
    const int dh = seg >> 4;
    const int wqq = (seg >> 3) & 1;
    const int dt = seg & 7;
    const int q0 = wqq * 32 + 8 * rr + 4 * hh;
    const int d = dh * 256 + dt * 32 + l31;
    f32x4 acc = {};
    for (int cc = 0; cc < nc; cc++) {
      const int bidc = ((w0 + cc) << 2) | b;
      const bf16x4 p = *(const bf16x4*)(partO + (size_t)bidc * 32768 +
                                        (size_t)(seg * 256 + tid) * 4);
      const f32x4 wv = *(const f32x4*)(&wgt[cc][q0]);
#pragma unroll
      for (int e = 0; e < 4; e++) acc[e] += wv[e] * (float)p[e];
    }
    const f32x4 li = *(const f32x4*)(&linv[q0]);
#pragma unroll
    for (int j = 0; j < 4; j++) {
      const int qq = q0 + j;
      *(bf16_t*)((char*)TB + qq * 1024 + ((d * 2) ^ ((qq & 7) << 4))) =
          (bf16_t)(acc[j] * li[j]);
    }
  }
  __syncthreads();

  // coalesced read + store: thread = (row q, 128-d quarter)
  const int row = tid >> 2;
  const int dq = (tid & 3) * 128;
  bf16_t* orow = o + ((size_t)(b * 4096 + s * 64 + row)) * 512 + dq;
#pragma unroll
  for (int jj = 0; jj < 16; jj++) {
    const int byte = row * 1024 + (((dq + jj * 8) * 2) ^ ((row & 7) << 4));
    *(bf16x8*)(orow + jj * 8) = *(const bf16x8*)((const char*)TB + byte);
  }
}

// ---------------------------------------------------------------------------
extern "C" void kernel_launch(void* const* d_in, const int* in_sizes, int n_in,
                              void* d_out, int out_size, void* d_ws, size_t ws_size,
                              hipStream_t stream) {
  const float* x_f = (const float*)d_in[0];   // [4,4096,512] fp32
  const float* wq_f = (const float*)d_in[1];  // [1536,512]   fp32
  const float* wp_f = (const float*)d_in[2];  // [512,512]    fp32
  float* out = (float*)d_out;                 // [4,4096,512] fp32

  // ws (bf16 unless noted): xb | wqb | wpb | q | k | vT | partO | stats
  bf16_t* xb = (bf16_t*)d_ws;                      // 16 MB (attn output)
  bf16_t* wqb = xb + (size_t)16384 * 512;          // 1.5 MB
  bf16_t* wpb = wqb + (size_t)1536 * 512;          // 0.5 MB
  bf16_t* q = wpb + (size_t)512 * 512;             // 16 MB
  bf16_t* kk = q + (size_t)16384 * 512;            // 16 MB
  bf16_t* vT = kk + (size_t)16384 * 512;           // 16 MB
  bf16_t* partO = vT + (size_t)16384 * 512;        // 1152*32768*2 = 75.5 MB
  float2* stats = (float2*)(partO + (size_t)1152 * 32768);  // 0.6 MB

  // 0) convert fp32 inputs -> bf16 (single launch)
  cvt3_kernel<<<9216, 256, 0, stream>>>(x_f, wq_f, wp_f, xb, wqb, wpb);

  // 1) qkv = x @ Wqkv^T ; v stored transposed (xb dead afterwards)
  gemm_bt_kernel<0><<<128 * 12, 256, 0, stream>>>(xb, wqb, q, kk, vT, nullptr);
  // 2a) attention partials (32x32 MFMA, counted-vmcnt pipeline)
  attn_part_kernel<<<1152, 256, 0, stream>>>(q, kk, vT, partO, stats);
  // 2b) combine partials -> xb
  attn_combine_kernel<<<256, 256, 0, stream>>>(partO, stats, xb);
  // 3) y = attn @ Wproj^T -> fp32 d_out
  gemm_bt_kernel<1><<<128 * 4, 256, 0, stream>>>(xb, wpb, nullptr, nullptr, nullptr, out);
}